// Round 9
// baseline (532.075 us; speedup 1.0000x reference)
//
#include <hip/hip_runtime.h>

// ResLSTM: B=4096, T=512, H=32. One wave64 per batch element.
// Lane l owns gate rows l (i|f) and l+64 (g|o).
//
// R9: DPP-systolic h broadcast. Evidence: readlane path = 407 us
// (33 readlane x ~6.5 cyc SGPR-write serialization), LDS path = 330 us
// (DS-pipe roofline: 16 waves/CU x 8 ds_read_b128 x 12 cyc = 1536 cyc/CU-step
// = 98.7% of observed). DPP (v_mov_b32 dpp wave_ror:1) is the only cross-lane
// path using neither pipe: 2-cyc VALU, no SGPR hazard, no DS slot.
//   - h replicated in both halves (upper lanes compute valid c,h via cndmask
//     reorg of the gate exchange), so a 64-lane rotate has period 32.
//   - weights pre-skewed per lane: slot s = W[row][(l + s*d) & 31], so the
//     register index is static while h rotates underneath.
//   - rotation direction d probed at runtime (rotate lane-id, readlane(2),
//     d = at2-2), folded into weight-load addresses: correct either way.
//   - two chains (A=h, B=shfl_xor(h,16)) cover K disjointly, halving the
//     rotation dependency chain.

static constexpr int T_LEN = 512;
static constexpr int H = 32;

__device__ __forceinline__ float rl_c(float v, int l) {
    return __int_as_float(__builtin_amdgcn_readlane(__float_as_int(v), l));
}

// wave_ror:1 = DPP ctrl 0x13C (full 64-lane rotate by one).
__device__ __forceinline__ float rot1(float v) {
    return __int_as_float(__builtin_amdgcn_update_dpp(
        0, __float_as_int(v), 0x13C, 0xF, 0xF, false));
}

// exp2-based sigmoid: sigmoid(x) = rcp(1 + exp2(x * -log2(e)))
__device__ __forceinline__ float sig_e2(float x_times_nlog2e) {
    return __builtin_amdgcn_rcpf(1.0f + __builtin_amdgcn_exp2f(x_times_nlog2e));
}

__global__ void
__attribute__((amdgpu_flat_work_group_size(256, 256), amdgpu_waves_per_eu(4, 4)))
reslstm_kernel(const float* __restrict__ x,
               const float* __restrict__ W_ih,
               const float* __restrict__ W_hh,
               const float* __restrict__ b_ih,
               const float* __restrict__ b_hh,
               const float* __restrict__ W_fc,
               const float* __restrict__ b_fc,
               float* __restrict__ out, int B)
{
    const int lane = threadIdx.x & 63;
    const int wv   = threadIdx.x >> 6;
    const int b    = (blockIdx.x << 2) + wv;
    if (b >= B) return;                       // wave-uniform guard

    // --- Probe wave_ror:1 direction (wave-uniform, one-time) ---
    // After one rotation, lane 2 holds original lane (2+d)'s value.
    int dstep;
    {
        const int pr  = __builtin_amdgcn_update_dpp(0, lane, 0x13C, 0xF, 0xF, false);
        const int at2 = __builtin_amdgcn_readlane(pr, 2);
        dstep = at2 - 2;                      // -1 or +1
    }

    // --- Skewed weight preload: slot s <-> h index (lane + s*dstep) & 31 ---
    float wa0[16], wb0[16], wa1[16], wb1[16];
    {
        const float* Wr0 = W_hh + (size_t)lane * H;          // i|f row
        const float* Wr1 = W_hh + (size_t)(lane + 64) * H;   // g|o row
        #pragma unroll
        for (int s = 0; s < 16; ++s) {
            const int cA = (lane + s * dstep) & 31;
            const int cB = (cA + 16) & 31;
            wa0[s] = Wr0[cA]; wb0[s] = Wr0[cB];
            wa1[s] = Wr1[cA]; wb1[s] = Wr1[cB];
        }
    }

    const float wih0  = W_ih[lane];
    const float wih1  = W_ih[lane + 64];
    const float bias0 = b_ih[lane] + b_hh[lane];
    const float bias1 = b_ih[lane + 64] + b_hh[lane + 64];

    // Branchless tanh-vs-sigmoid for the r1 gate: tanh(x)=2*sigmoid(2x)-1.
    const bool  lo = (lane < 32);
    constexpr float NL2E = -1.4426950408889634f;
    const float e1 = lo ? 2.0f * NL2E : NL2E;
    const float s1 = lo ? 2.0f : 1.0f;
    const float t1 = lo ? -1.0f : 0.0f;

    float h = 0.0f, c = 0.0f;                 // replicated: lane l <-> unit l&31
    const float* xrow = x + (size_t)b * T_LEN;

// Volatile pins (R7-style, known-neutral-at-worst): forbid sinking the
// weight loads into the loop.
#define PIN16(A)                                                          \
    asm volatile("" : "+v"(A[0]),  "+v"(A[1]),  "+v"(A[2]),  "+v"(A[3]),  \
                      "+v"(A[4]),  "+v"(A[5]),  "+v"(A[6]),  "+v"(A[7]),  \
                      "+v"(A[8]),  "+v"(A[9]),  "+v"(A[10]), "+v"(A[11]), \
                      "+v"(A[12]), "+v"(A[13]), "+v"(A[14]), "+v"(A[15]))

    for (int tc = 0; tc < T_LEN / 64; ++tc) {
        const float xv = xrow[(tc << 6) + lane];   // coalesced 64-float chunk
        #pragma unroll 4
        for (int tt = 0; tt < 64; ++tt) {
            PIN16(wa0); PIN16(wb0); PIN16(wa1); PIN16(wb1);
            const float xt = rl_c(xv, tt);         // x[b][t], wave-uniform
            float hA = h;                          // chain A: k = lane+s*d
            float hB = __shfl_xor(h, 16);          // chain B: k = lane+16+s*d
            float acA0 = __builtin_fmaf(xt, wih0, bias0);
            float acA1 = __builtin_fmaf(xt, wih1, bias1);
            float acB0 = 0.0f, acB1 = 0.0f;
            #pragma unroll
            for (int s = 0; s < 16; ++s) {
                acA0 = __builtin_fmaf(wa0[s], hA, acA0);
                acA1 = __builtin_fmaf(wa1[s], hA, acA1);
                acB0 = __builtin_fmaf(wb0[s], hB, acB0);
                acB1 = __builtin_fmaf(wb1[s], hB, acB1);
                if (s < 15) { hA = rot1(hA); hB = rot1(hB); }
            }
            const float aA = acA0 + acB0;          // i|f pre-activation
            const float aB = acA1 + acB1;          // g|o pre-activation
            const float g0 = sig_e2(aA * NL2E);                       // i | f
            const float g1 = __builtin_fmaf(s1, sig_e2(aB * e1), t1); // g | o
            const float fo = __shfl_xor(g0, 32);   // lo lanes: f ; hi lanes: i
            const float og = __shfl_xor(g1, 32);   // lo lanes: o ; hi lanes: g
            // Reorganize so BOTH halves compute the true c,h of unit lane&31:
            const float ff = lo ? fo : g0;
            const float ii = lo ? g0 : fo;
            const float gg = lo ? g1 : og;
            const float oo = lo ? og : g1;
            c = __builtin_fmaf(ff, c, ii * gg);                       // f*c+i*g
            const float th = __builtin_fmaf(2.0f, sig_e2(c * (2.0f * NL2E)), -1.0f);
            h = oo * th;                                              // o*tanh(c)
        }
    }
#undef PIN16

    // out[b] = sum_j h[j]*W_fc[j] + b_fc  (h replicated; reduce lanes 0..31)
    float val = lo ? h * W_fc[lane & (H - 1)] : 0.0f;
    #pragma unroll
    for (int off = 32; off >= 1; off >>= 1)
        val += __shfl_xor(val, off);
    if (lane == 0) out[b] = val + b_fc[0];
}

extern "C" void kernel_launch(void* const* d_in, const int* in_sizes, int n_in,
                              void* d_out, int out_size, void* d_ws, size_t ws_size,
                              hipStream_t stream) {
    const float* x    = (const float*)d_in[0];
    const float* W_ih = (const float*)d_in[1];
    const float* W_hh = (const float*)d_in[2];
    const float* b_ih = (const float*)d_in[3];
    const float* b_hh = (const float*)d_in[4];
    const float* W_fc = (const float*)d_in[5];
    const float* b_fc = (const float*)d_in[6];
    float* out = (float*)d_out;
    const int B = in_sizes[0] / T_LEN;        // 4096
    dim3 block(256);                          // 4 waves = 4 batch elements
    dim3 grid((B + 3) / 4);                   // 1024 blocks -> 4 waves/SIMD
    reslstm_kernel<<<grid, block, 0, stream>>>(x, W_ih, W_hh, b_ih, b_hh,
                                               W_fc, b_fc, out, B);
}

// Round 12
// 461.096 us; speedup vs baseline: 1.1539x; 1.1539x over previous
//
#include <hip/hip_runtime.h>

// ResLSTM via MFMA: B=4096, T=512, H=32. ONE WAVE PER 16 BATCHES.
// Recurrent matvec W_hh(128x32) @ h(32x16) = 8 mfma_f32_16x16x32_f16 tiles,
// W_hh split hi+lo fp16 (16 MFMA/step, W exact to ~2^-22). h carried fp16
// (err ~2^-10|h|/step -> ~1e-4 final, threshold 3.4e-3). x*W_ih + biases in
// exact fp32 as the MFMA C initializer.
//
// Why: R4-R9 proved the 1-batch/wave mapping is pinned at 316-330 us by the
// DS-pipe roofline (16 waves/CU x 8 ds_read_b128 x 12 cyc = 1536 cyc/CU-step
// = 98.7% of observed); readlane (407) and DPP (532) are worse walls. This
// mapping amortizes the h-broadcast over 16 batches and moves the 8.6G MACs
// to the idle matrix pipe.
//
// R12 fix vs R11: h-publish for units 16..31 wrote LDS offset 32+4q but the
// B-fragment read consumes positions 0..31 -> positions 16..31 were never
// written (uninitialized LDS -> NaN). Correct offset is 16+4q.
//
// Layouts (gfx950, verified m89/m120): C/D col=lane&15,row=(lane>>4)*4+reg;
// A[m=lane&15][k=(lane>>4)*8+j]; B[k=(lane>>4)*8+j][n=lane&15].

typedef _Float16 f16;
typedef _Float16 f16x4 __attribute__((ext_vector_type(4)));
typedef _Float16 f16x8 __attribute__((ext_vector_type(8)));
typedef float    f32x4 __attribute__((ext_vector_type(4)));

static constexpr int T_LEN   = 512;
static constexpr int H       = 32;
static constexpr int XSTRIDE = 516;  // dwords per batch row of x-stage (pad)
static constexpr int HSTRIDE = 40;   // halves per batch row of h-buffer (80 B)

__device__ __forceinline__ float sig_e2(float xn) {  // xn = x * -log2(e)
    return __builtin_amdgcn_rcpf(1.0f + __builtin_amdgcn_exp2f(xn));
}

__global__ void
__attribute__((amdgpu_flat_work_group_size(64, 64), amdgpu_waves_per_eu(1, 1)))
reslstm_mfma(const float* __restrict__ x,
             const float* __restrict__ W_ih,
             const float* __restrict__ W_hh,
             const float* __restrict__ b_ih,
             const float* __restrict__ b_hh,
             const float* __restrict__ W_fc,
             const float* __restrict__ b_fc,
             float* __restrict__ out)
{
    __shared__ __align__(16) float xlds[16 * XSTRIDE];   // ~33 KB
    __shared__ __align__(16) f16   hlds[16 * HSTRIDE];   // 1.25 KB

    const int lane = threadIdx.x;      // block = exactly 1 wave
    const int n    = lane & 15;        // batch column
    const int q    = lane >> 4;        // quad
    const int g    = blockIdx.x;       // batch group (16 batches)

    // ---- stage x[g*16 .. +15][0..511] into padded LDS rows ----
    {
        const float4* xg = reinterpret_cast<const float4*>(x) + (size_t)g * 2048;
        #pragma unroll 4
        for (int i = 0; i < 32; ++i) {
            const int idx4 = i * 64 + lane;        // 0..2047
            const int row  = idx4 >> 7;            // 128 float4 per row
            const int t4   = idx4 & 127;
            const float4 v = xg[idx4];
            *reinterpret_cast<float4*>(&xlds[row * XSTRIDE + 4 * t4]) = v;
        }
    }
    // staging visibility across lanes before the t-loop reads
    asm volatile("s_waitcnt lgkmcnt(0)" ::: "memory");

    // ---- A fragments: W_hh hi/lo fp16 per tile (tile t = gate rows 16t..16t+15) ----
    f16x8 ahi[8], alo[8];
    #pragma unroll
    for (int t = 0; t < 8; ++t) {
        const float* wrow = W_hh + (size_t)(16 * t + n) * H + 8 * q;  // A row m=n, k=8q+j
        #pragma unroll
        for (int j = 0; j < 8; ++j) {
            const float w = wrow[j];
            const f16 hi  = (f16)w;
            ahi[t][j] = hi;
            alo[t][j] = (f16)(w - (float)hi);
        }
    }

    // ---- per-lane fp32 W_ih & bias for C-init rows 16t+4q+r (C/D layout) ----
    float wi[32], bs[32];
    #pragma unroll
    for (int t = 0; t < 8; ++t) {
        #pragma unroll
        for (int r = 0; r < 4; ++r) {
            const int R = 16 * t + 4 * q + r;
            wi[4 * t + r] = W_ih[R];
            bs[4 * t + r] = b_ih[R] + b_hh[R];
        }
    }

    // ---- W_fc for this lane's units (slots 0..3 -> 4q+r, 4..7 -> 16+4q+r) ----
    float wfc[8];
    #pragma unroll
    for (int r = 0; r < 4; ++r) {
        wfc[r]     = W_fc[4 * q + r];
        wfc[r + 4] = W_fc[16 + 4 * q + r];
    }

    constexpr float NL2E = -1.4426950408889634f;

    float cst[8], h[8];
    #pragma unroll
    for (int s = 0; s < 8; ++s) { cst[s] = 0.0f; h[s] = 0.0f; }

    const float* xrow = &xlds[n * XSTRIDE];
    f16* hw = &hlds[n * HSTRIDE];
    const f16x8* hrd = reinterpret_cast<const f16x8*>(&hlds[n * HSTRIDE + 8 * q]);

    for (int t = 0; t < T_LEN; ++t) {
        // publish h(t-1): lane holds units {4q+r} (slots 0-3), {16+4q+r} (4-7)
        f16x4 w0, w1;
        w0[0] = (f16)h[0]; w0[1] = (f16)h[1]; w0[2] = (f16)h[2]; w0[3] = (f16)h[3];
        w1[0] = (f16)h[4]; w1[1] = (f16)h[5]; w1[2] = (f16)h[6]; w1[3] = (f16)h[7];
        *reinterpret_cast<f16x4*>(&hw[4 * q])      = w0;   // units 4q..4q+3
        *reinterpret_cast<f16x4*>(&hw[16 + 4 * q]) = w1;   // units 16+4q..+3
        // ensure cross-lane visibility before the B-frag read (wave-sync)
        asm volatile("s_waitcnt lgkmcnt(0)" ::: "memory");

        // B fragment: h[k=8q..8q+7][batch n], and this step's x
        const f16x8 bh = *hrd;
        const float xf = xrow[t];

        // C init = x*W_ih + bias (exact fp32), then += (Whi + Wlo) * h
        f32x4 C[8];
        #pragma unroll
        for (int tt = 0; tt < 8; ++tt) {
            f32x4 c0;
            c0[0] = __builtin_fmaf(xf, wi[4 * tt + 0], bs[4 * tt + 0]);
            c0[1] = __builtin_fmaf(xf, wi[4 * tt + 1], bs[4 * tt + 1]);
            c0[2] = __builtin_fmaf(xf, wi[4 * tt + 2], bs[4 * tt + 2]);
            c0[3] = __builtin_fmaf(xf, wi[4 * tt + 3], bs[4 * tt + 3]);
            c0 = __builtin_amdgcn_mfma_f32_16x16x32_f16(ahi[tt], bh, c0, 0, 0, 0);
            c0 = __builtin_amdgcn_mfma_f32_16x16x32_f16(alo[tt], bh, c0, 0, 0, 0);
            C[tt] = c0;
        }

        // activations: slot s -> unit (s<4 ? 4q+s : 16+4q+s-4)
        // gate tiles: i = 0/1, f = 2/3, g = 4/5, o = 6/7
        #pragma unroll
        for (int s = 0; s < 8; ++s) {
            const int te = (s < 4) ? 0 : 1;
            const int r  = s & 3;
            const float aI = C[0 + te][r];
            const float aF = C[2 + te][r];
            const float aG = C[4 + te][r];
            const float aO = C[6 + te][r];
            const float gi = sig_e2(aI * NL2E);
            const float gf = sig_e2(aF * NL2E);
            const float gg = __builtin_fmaf(2.0f, sig_e2(aG * (2.0f * NL2E)), -1.0f);
            const float go = sig_e2(aO * NL2E);
            const float cc = __builtin_fmaf(gf, cst[s], gi * gg);
            cst[s] = cc;
            const float th = __builtin_fmaf(2.0f, sig_e2(cc * (2.0f * NL2E)), -1.0f);
            h[s] = go * th;
        }
    }

    // ---- FC: out[b] = sum_u h[u]*W_fc[u] + b_fc; reduce the 4 quads of col n
    float val = 0.0f;
    #pragma unroll
    for (int s = 0; s < 8; ++s) val = __builtin_fmaf(h[s], wfc[s], val);
    val += __shfl_xor(val, 16);
    val += __shfl_xor(val, 32);
    if (lane < 16) out[g * 16 + n] = val + b_fc[0];
}

extern "C" void kernel_launch(void* const* d_in, const int* in_sizes, int n_in,
                              void* d_out, int out_size, void* d_ws, size_t ws_size,
                              hipStream_t stream) {
    const float* x    = (const float*)d_in[0];
    const float* W_ih = (const float*)d_in[1];
    const float* W_hh = (const float*)d_in[2];
    const float* b_ih = (const float*)d_in[3];
    const float* b_hh = (const float*)d_in[4];
    const float* W_fc = (const float*)d_in[5];
    const float* b_fc = (const float*)d_in[6];
    float* out = (float*)d_out;
    const int B = in_sizes[0] / T_LEN;        // 4096
    dim3 block(64);                           // one wave
    dim3 grid(B / 16);                        // 256 blocks -> 1 per CU
    reslstm_mfma<<<grid, block, 0, stream>>>(x, W_ih, W_hh, b_ih, b_hh,
                                             W_fc, b_fc, out);
}